// Round 1
// baseline (7716.669 us; speedup 1.0000x reference)
//
#include <hip/hip_runtime.h>
#include <cstdint>
#include <cmath>

#define NB 4
#define NQn 128
#define QD 512
#define EMBD 512
#define NH 8
#define DHn 64
#define VOCAB 20000
#define WDn 300
#define VCHUNK 128
#define NCHUNK 157   // ceil(20000/128)

// PRNG variant for jax.random.uniform(key(42)) bits:
// 0: partitionable, bits = out0 ^ out1   (guess #1)
// 1: partitionable, bits = out0
// 2: partitionable, bits = out1
// 3: legacy (non-partitionable) split-iota mode
#define PRNG_MODE 0

__device__ __forceinline__ void tf_rounds(uint32_t &x0, uint32_t &x1) {
  const uint32_t ks0 = 0u;
  const uint32_t ks1 = 42u;
  const uint32_t ks2 = 0x1BD11BDAu ^ 42u;
  x0 += ks0; x1 += ks1;
#define TFR(r) { x0 += x1; x1 = (x1 << (r)) | (x1 >> (32 - (r))); x1 ^= x0; }
  TFR(13) TFR(15) TFR(26) TFR(6)  x0 += ks1; x1 += ks2 + 1u;
  TFR(17) TFR(29) TFR(16) TFR(24) x0 += ks2; x1 += ks0 + 2u;
  TFR(13) TFR(15) TFR(26) TFR(6)  x0 += ks0; x1 += ks1 + 3u;
  TFR(17) TFR(29) TFR(16) TFR(24) x0 += ks1; x1 += ks2 + 4u;
  TFR(13) TFR(15) TFR(26) TFR(6)  x0 += ks2; x1 += ks0 + 5u;
#undef TFR
}

__device__ __forceinline__ uint32_t rand_bits(uint32_t l) {
#if PRNG_MODE == 3
  const uint32_t Hh = 40960000u;  // half of 4*8*128*20000
  uint32_t x0, x1;
  if (l < Hh) { x0 = l;      x1 = l + Hh; tf_rounds(x0, x1); return x0; }
  else        { x0 = l - Hh; x1 = l;      tf_rounds(x0, x1); return x1; }
#else
  uint32_t x0 = 0u, x1 = l;
  tf_rounds(x0, x1);
#if PRNG_MODE == 0
  return x0 ^ x1;
#elif PRNG_MODE == 1
  return x0;
#else
  return x1;
#endif
#endif
}

// returns log(-log(u)) for element with linear index l (subtract from scaled dots)
__device__ __forceinline__ float gumbel_ll(uint32_t l) {
  uint32_t bits = rand_bits(l);
  float f = __uint_as_float((bits >> 9) | 0x3f800000u) - 1.0f;
  float u = fmaxf(f, 1.17549435e-38f);   // matches max(tiny, f*(1-tiny)+tiny) exactly
  return logf(-logf(u));
}

// ---------------- K1: LayerNorm + Q projection ----------------
__global__ void ln_qproj_kernel(const float* __restrict__ queries,
                                const float* __restrict__ Wq,
                                const float* __restrict__ ln_g,
                                const float* __restrict__ ln_b,
                                float* __restrict__ q_ws) {
  __shared__ float xn[4][QD];
  const int tid = threadIdx.x;
  const int wave = tid >> 6, lane = tid & 63;
  const int r = blockIdx.x * 4 + wave;   // global row (b*128+q), 0..511

  float vals[8];
  float s = 0.f;
#pragma unroll
  for (int j = 0; j < 8; ++j) { vals[j] = queries[r * QD + j * 64 + lane]; s += vals[j]; }
#pragma unroll
  for (int m = 32; m >= 1; m >>= 1) s += __shfl_xor(s, m, 64);
  const float mu = s * (1.f / 512.f);
  float ss = 0.f;
#pragma unroll
  for (int j = 0; j < 8; ++j) { float d = vals[j] - mu; ss += d * d; }
#pragma unroll
  for (int m = 32; m >= 1; m >>= 1) ss += __shfl_xor(ss, m, 64);
  const float rstd = 1.f / sqrtf(ss * (1.f / 512.f) + 1e-5f);
#pragma unroll
  for (int j = 0; j < 8; ++j) {
    int e = j * 64 + lane;
    xn[wave][e] = (vals[j] - mu) * rstd * ln_g[e] + ln_b[e];
  }
  __syncthreads();
  // q = xn @ Wq ; each thread: 2 output cols x 4 rows
  for (int e = tid; e < EMBD; e += 256) {
    float a0 = 0.f, a1 = 0.f, a2 = 0.f, a3 = 0.f;
    for (int i = 0; i < QD; ++i) {
      float w = Wq[i * EMBD + e];
      a0 += xn[0][i] * w; a1 += xn[1][i] * w; a2 += xn[2][i] * w; a3 += xn[3][i] * w;
    }
    int r0 = blockIdx.x * 4;
    q_ws[(r0 + 0) * EMBD + e] = a0;
    q_ws[(r0 + 1) * EMBD + e] = a1;
    q_ws[(r0 + 2) * EMBD + e] = a2;
    q_ws[(r0 + 3) * EMBD + e] = a3;
  }
}

// ---------------- K2: k = glove @ Wk (20000 x 300 x 512) ----------------
#define BKk 60
__global__ void kproj_kernel(const float* __restrict__ glove,
                             const float* __restrict__ Wk,
                             float* __restrict__ k_ws) {
  __shared__ float As[64 * BKk];      // [row][w], stride 60
  __shared__ float Bs[BKk * 64];      // [w][col]
  const int tid = threadIdx.x;
  const int v0 = blockIdx.x * 64, n0 = blockIdx.y * 64;
  const int ty = tid >> 4, tx = tid & 15;
  float acc[4][4] = {};
  for (int s = 0; s < 5; ++s) {
    const int w0 = s * BKk;
    __syncthreads();
    for (int f = tid; f < 64 * 15; f += 256) {
      int row = f / 15, c4 = f % 15;
      int v = v0 + row;
      float4 g4 = (v < VOCAB) ? *(const float4*)&glove[(size_t)v * WDn + w0 + c4 * 4]
                              : make_float4(0.f, 0.f, 0.f, 0.f);
      *(float4*)&As[row * BKk + c4 * 4] = g4;
    }
    for (int f = tid; f < BKk * 16; f += 256) {
      int row = f / 16, c4 = f % 16;
      *(float4*)&Bs[row * 64 + c4 * 4] = *(const float4*)&Wk[(size_t)(w0 + row) * EMBD + n0 + c4 * 4];
    }
    __syncthreads();
    for (int w = 0; w < BKk; ++w) {
      float4 bv = *(float4*)&Bs[w * 64 + tx * 4];
      float a0 = As[(ty * 4 + 0) * BKk + w];
      float a1 = As[(ty * 4 + 1) * BKk + w];
      float a2 = As[(ty * 4 + 2) * BKk + w];
      float a3 = As[(ty * 4 + 3) * BKk + w];
      acc[0][0] += a0 * bv.x; acc[0][1] += a0 * bv.y; acc[0][2] += a0 * bv.z; acc[0][3] += a0 * bv.w;
      acc[1][0] += a1 * bv.x; acc[1][1] += a1 * bv.y; acc[1][2] += a1 * bv.z; acc[1][3] += a1 * bv.w;
      acc[2][0] += a2 * bv.x; acc[2][1] += a2 * bv.y; acc[2][2] += a2 * bv.z; acc[2][3] += a2 * bv.w;
      acc[3][0] += a3 * bv.x; acc[3][1] += a3 * bv.y; acc[3][2] += a3 * bv.z; acc[3][3] += a3 * bv.w;
    }
  }
#pragma unroll
  for (int i = 0; i < 4; ++i) {
    int v = v0 + ty * 4 + i;
    if (v < VOCAB) {
      float4 st = make_float4(acc[i][0], acc[i][1], acc[i][2], acc[i][3]);
      *(float4*)&k_ws[(size_t)v * EMBD + n0 + tx * 4] = st;
    }
  }
}

// ---------------- K3: scores + gumbel noise + per-chunk argmax ----------------
__global__ void score_kernel(const float* __restrict__ q_ws,
                             const float* __restrict__ k_ws,
                             float* __restrict__ pval,
                             int* __restrict__ pidx) {
  __shared__ float Qs[64 * 68];
  __shared__ float Ks[128 * 68];
  const int tid = threadIdx.x;
  const int chunk = blockIdx.x, rowtile = blockIdx.y, h = blockIdx.z;
  const int v0 = chunk * VCHUNK;
  const int ty = tid >> 4, tx = tid & 15;

  for (int f = tid; f < 64 * 16; f += 256) {
    int row = f >> 4, c4 = f & 15;
    *(float4*)&Qs[row * 68 + c4 * 4] =
        *(const float4*)&q_ws[(size_t)(rowtile * 64 + row) * EMBD + h * DHn + c4 * 4];
  }
  for (int f = tid; f < 128 * 16; f += 256) {
    int row = f >> 4, c4 = f & 15;
    int v = v0 + row;
    float4 k4 = (v < VOCAB) ? *(const float4*)&k_ws[(size_t)v * EMBD + h * DHn + c4 * 4]
                            : make_float4(0.f, 0.f, 0.f, 0.f);
    *(float4*)&Ks[row * 68 + c4 * 4] = k4;
  }
  __syncthreads();

  float acc[4][8] = {};
#pragma unroll
  for (int d0 = 0; d0 < DHn; d0 += 4) {
    float4 qf[4], kf[8];
#pragma unroll
    for (int i = 0; i < 4; ++i) qf[i] = *(float4*)&Qs[(ty * 4 + i) * 68 + d0];
#pragma unroll
    for (int j = 0; j < 8; ++j) kf[j] = *(float4*)&Ks[(tx + 16 * j) * 68 + d0];
#pragma unroll
    for (int i = 0; i < 4; ++i)
#pragma unroll
      for (int j = 0; j < 8; ++j)
        acc[i][j] += qf[i].x * kf[j].x + qf[i].y * kf[j].y + qf[i].z * kf[j].z + qf[i].w * kf[j].w;
  }

#pragma unroll
  for (int i = 0; i < 4; ++i) {
    const int r = rowtile * 64 + ty * 4 + i;     // 0..511 within head
    const int b = r >> 7, q = r & 127;
    const uint32_t base = (uint32_t)((b * NH + h) * NQn + q) * (uint32_t)VOCAB;
    float best = -INFINITY; int bidx = 0x7fffffff;
#pragma unroll
    for (int j = 0; j < 8; ++j) {
      int v = v0 + tx + 16 * j;
      if (v < VOCAB) {
        float g = gumbel_ll(base + (uint32_t)v);
        float val = acc[i][j] * 0.125f - g;      // dots*scale - log(-log(u)); TAU=1
        if (val > best || (val == best && v < bidx)) { best = val; bidx = v; }
      }
    }
#pragma unroll
    for (int m = 8; m >= 1; m >>= 1) {
      float ov = __shfl_xor(best, m, 64);
      int   oi = __shfl_xor(bidx, m, 64);
      if (ov > best || (ov == best && oi < bidx)) { best = ov; bidx = oi; }
    }
    if (tx == 0) {
      int prow = h * 512 + r;
      pval[(size_t)prow * NCHUNK + chunk] = best;
      pidx[(size_t)prow * NCHUNK + chunk] = bidx;
    }
  }
}

// ---------------- K4: reduce chunk partials -> final argmax ----------------
__global__ void argmax_reduce_kernel(const float* __restrict__ pval,
                                     const int* __restrict__ pidx,
                                     int* __restrict__ idxf) {
  const int tid = threadIdx.x;
  const int wave = tid >> 6, lane = tid & 63;
  const int row = blockIdx.x * 4 + wave;   // 0..4095 = h*512 + (b*128+q)
  float best = -INFINITY; int bidx = 0x7fffffff;
  for (int c = lane; c < NCHUNK; c += 64) {
    float v = pval[(size_t)row * NCHUNK + c];
    int   i = pidx[(size_t)row * NCHUNK + c];
    if (v > best || (v == best && i < bidx)) { best = v; bidx = i; }
  }
#pragma unroll
  for (int m = 32; m >= 1; m >>= 1) {
    float ov = __shfl_xor(best, m, 64);
    int   oi = __shfl_xor(bidx, m, 64);
    if (ov > best || (ov == best && oi < bidx)) { best = ov; bidx = oi; }
  }
  if (lane == 0) {
    int h = row >> 9, r = row & 511, b = r >> 7, q = r & 127;
    idxf[(b * NH + h) * NQn + q] = bidx;
  }
}

// ---------------- K5: gather + V projection + out proj + residual ----------------
__global__ void out_kernel(const float* __restrict__ queries,
                           const float* __restrict__ glove,
                           const float* __restrict__ Wv,
                           const float* __restrict__ Wout,
                           const float* __restrict__ b_out,
                           const int* __restrict__ idxf,
                           float* __restrict__ out) {
  __shared__ float gl[4][NH][WDn];   // 38400 B
  __shared__ float vrow[4][EMBD];    // 8192 B
  __shared__ int idxs[4][NH];
  const int tid = threadIdx.x;
  const int r0 = blockIdx.x * 4;
  if (tid < 32) {
    int rr = tid >> 3, hh = tid & 7;
    int r = r0 + rr, b = r >> 7, q = r & 127;
    idxs[rr][hh] = idxf[(b * NH + hh) * NQn + q];
  }
  __syncthreads();
  for (int f = tid; f < 32 * 75; f += 256) {
    int rp = f / 75, c4 = f % 75;
    int rr = rp >> 3, hh = rp & 7;
    *(float4*)&gl[rr][hh][c4 * 4] = *(const float4*)&glove[(size_t)idxs[rr][hh] * WDn + c4 * 4];
  }
  __syncthreads();
  for (int e = tid; e < EMBD; e += 256) {
    float a0 = 0.f, a1 = 0.f, a2 = 0.f, a3 = 0.f;
    int hh = e >> 6;
    for (int w = 0; w < WDn; ++w) {
      float wv = Wv[(size_t)w * EMBD + e];
      a0 += gl[0][hh][w] * wv; a1 += gl[1][hh][w] * wv;
      a2 += gl[2][hh][w] * wv; a3 += gl[3][hh][w] * wv;
    }
    vrow[0][e] = a0; vrow[1][e] = a1; vrow[2][e] = a2; vrow[3][e] = a3;
  }
  __syncthreads();
  for (int j = tid; j < EMBD; j += 256) {
    float a0 = 0.f, a1 = 0.f, a2 = 0.f, a3 = 0.f;
    for (int e = 0; e < EMBD; ++e) {
      float wo = Wout[(size_t)e * QD + j];
      a0 += vrow[0][e] * wo; a1 += vrow[1][e] * wo;
      a2 += vrow[2][e] * wo; a3 += vrow[3][e] * wo;
    }
    float bb = b_out[j];
    out[(size_t)(r0 + 0) * QD + j] = queries[(size_t)(r0 + 0) * QD + j] + a0 + bb;
    out[(size_t)(r0 + 1) * QD + j] = queries[(size_t)(r0 + 1) * QD + j] + a1 + bb;
    out[(size_t)(r0 + 2) * QD + j] = queries[(size_t)(r0 + 2) * QD + j] + a2 + bb;
    out[(size_t)(r0 + 3) * QD + j] = queries[(size_t)(r0 + 3) * QD + j] + a3 + bb;
  }
}

extern "C" void kernel_launch(void* const* d_in, const int* in_sizes, int n_in,
                              void* d_out, int out_size, void* d_ws, size_t ws_size,
                              hipStream_t stream) {
  const float* queries = (const float*)d_in[0];
  const float* glove   = (const float*)d_in[1];
  const float* Wq      = (const float*)d_in[2];
  const float* Wk      = (const float*)d_in[3];
  const float* Wv      = (const float*)d_in[4];
  const float* Wout    = (const float*)d_in[5];
  const float* b_out   = (const float*)d_in[6];
  const float* ln_g    = (const float*)d_in[7];
  const float* ln_b    = (const float*)d_in[8];
  float* out = (float*)d_out;

  // workspace layout (floats): q[512*512] | k[20000*512] | pval[4096*157] | pidx | idxf
  float* ws   = (float*)d_ws;
  float* q_ws = ws;
  float* k_ws = q_ws + (size_t)NB * NQn * EMBD;
  float* pval = k_ws + (size_t)VOCAB * EMBD;
  int*   pidx = (int*)(pval + (size_t)NH * 512 * NCHUNK);
  int*   idxf = (int*)((float*)pidx + (size_t)NH * 512 * NCHUNK);
  // total ~47.2 MB

  hipLaunchKernelGGL(ln_qproj_kernel, dim3(128), dim3(256), 0, stream,
                     queries, Wq, ln_g, ln_b, q_ws);
  hipLaunchKernelGGL(kproj_kernel, dim3(313, 8), dim3(256), 0, stream,
                     glove, Wk, k_ws);
  hipLaunchKernelGGL(score_kernel, dim3(NCHUNK, 8, NH), dim3(256), 0, stream,
                     q_ws, k_ws, pval, pidx);
  hipLaunchKernelGGL(argmax_reduce_kernel, dim3(1024), dim3(256), 0, stream,
                     pval, pidx, idxf);
  hipLaunchKernelGGL(out_kernel, dim3(128), dim3(256), 0, stream,
                     queries, glove, Wv, Wout, b_out, idxf, out);
}

// Round 2
// 7231.045 us; speedup vs baseline: 1.0672x; 1.0672x over previous
//
#include <hip/hip_runtime.h>
#include <cstdint>
#include <cmath>

#define NB 4
#define NQn 128
#define QD 512
#define EMBD 512
#define NH 8
#define DHn 64
#define VOCAB 20000
#define WDn 300
#define VCHUNK 128
#define NCHUNK 157   // ceil(20000/128)

// PRNG variant (verified R1: partitionable threefry, bits = out0 ^ out1)
__device__ __forceinline__ void tf_rounds(uint32_t &x0, uint32_t &x1) {
  const uint32_t ks0 = 0u;
  const uint32_t ks1 = 42u;
  const uint32_t ks2 = 0x1BD11BDAu ^ 42u;
  x0 += ks0; x1 += ks1;
#define TFR(r) { x0 += x1; x1 = (x1 << (r)) | (x1 >> (32 - (r))); x1 ^= x0; }
  TFR(13) TFR(15) TFR(26) TFR(6)  x0 += ks1; x1 += ks2 + 1u;
  TFR(17) TFR(29) TFR(16) TFR(24) x0 += ks2; x1 += ks0 + 2u;
  TFR(13) TFR(15) TFR(26) TFR(6)  x0 += ks0; x1 += ks1 + 3u;
  TFR(17) TFR(29) TFR(16) TFR(24) x0 += ks1; x1 += ks2 + 4u;
  TFR(13) TFR(15) TFR(26) TFR(6)  x0 += ks2; x1 += ks0 + 5u;
#undef TFR
}

__device__ __forceinline__ uint32_t rand_bits(uint32_t l) {
  uint32_t x0 = 0u, x1 = l;
  tf_rounds(x0, x1);
  return x0 ^ x1;
}

// returns log(-log(u)) for element with linear index l (subtract from scaled dots)
__device__ __forceinline__ float gumbel_ll(uint32_t l) {
  uint32_t bits = rand_bits(l);
  float f = __uint_as_float((bits >> 9) | 0x3f800000u) - 1.0f;
  float u = fmaxf(f, 1.17549435e-38f);
  return logf(-logf(u));
}

// ---------------- K1: LayerNorm + Q projection ----------------
__global__ __launch_bounds__(256, 4) void ln_qproj_kernel(
                                const float* __restrict__ queries,
                                const float* __restrict__ Wq,
                                const float* __restrict__ ln_g,
                                const float* __restrict__ ln_b,
                                float* __restrict__ q_ws) {
  __shared__ float xn[4][QD];
  const int tid = threadIdx.x;
  const int wave = tid >> 6, lane = tid & 63;
  const int r = blockIdx.x * 4 + wave;   // global row (b*128+q), 0..511

  float vals[8];
  float s = 0.f;
#pragma unroll
  for (int j = 0; j < 8; ++j) { vals[j] = queries[r * QD + j * 64 + lane]; s += vals[j]; }
#pragma unroll
  for (int m = 32; m >= 1; m >>= 1) s += __shfl_xor(s, m, 64);
  const float mu = s * (1.f / 512.f);
  float ss = 0.f;
#pragma unroll
  for (int j = 0; j < 8; ++j) { float d = vals[j] - mu; ss += d * d; }
#pragma unroll
  for (int m = 32; m >= 1; m >>= 1) ss += __shfl_xor(ss, m, 64);
  const float rstd = 1.f / sqrtf(ss * (1.f / 512.f) + 1e-5f);
#pragma unroll
  for (int j = 0; j < 8; ++j) {
    int e = j * 64 + lane;
    xn[wave][e] = (vals[j] - mu) * rstd * ln_g[e] + ln_b[e];
  }
  __syncthreads();
  for (int e = tid; e < EMBD; e += 256) {
    float a0 = 0.f, a1 = 0.f, a2 = 0.f, a3 = 0.f;
    for (int i = 0; i < QD; ++i) {
      float w = Wq[i * EMBD + e];
      a0 += xn[0][i] * w; a1 += xn[1][i] * w; a2 += xn[2][i] * w; a3 += xn[3][i] * w;
    }
    int r0 = blockIdx.x * 4;
    q_ws[(r0 + 0) * EMBD + e] = a0;
    q_ws[(r0 + 1) * EMBD + e] = a1;
    q_ws[(r0 + 2) * EMBD + e] = a2;
    q_ws[(r0 + 3) * EMBD + e] = a3;
  }
}

// ---------------- K2: k = glove @ Wk (20000 x 300 x 512) ----------------
#define BKk 60
__global__ __launch_bounds__(256, 4) void kproj_kernel(
                             const float* __restrict__ glove,
                             const float* __restrict__ Wk,
                             float* __restrict__ k_ws) {
  __shared__ float As[64 * BKk];      // [row][w], stride 60
  __shared__ float Bs[BKk * 64];      // [w][col]
  const int tid = threadIdx.x;
  const int v0 = blockIdx.x * 64, n0 = blockIdx.y * 64;
  const int ty = tid >> 4, tx = tid & 15;
  float acc[4][4] = {};
  for (int s = 0; s < 5; ++s) {
    const int w0 = s * BKk;
    __syncthreads();
    for (int f = tid; f < 64 * 15; f += 256) {
      int row = f / 15, c4 = f % 15;
      int v = v0 + row;
      float4 g4 = (v < VOCAB) ? *(const float4*)&glove[(size_t)v * WDn + w0 + c4 * 4]
                              : make_float4(0.f, 0.f, 0.f, 0.f);
      *(float4*)&As[row * BKk + c4 * 4] = g4;
    }
    for (int f = tid; f < BKk * 16; f += 256) {
      int row = f / 16, c4 = f % 16;
      *(float4*)&Bs[row * 64 + c4 * 4] = *(const float4*)&Wk[(size_t)(w0 + row) * EMBD + n0 + c4 * 4];
    }
    __syncthreads();
    for (int w = 0; w < BKk; ++w) {
      float4 bv = *(float4*)&Bs[w * 64 + tx * 4];
      float a0 = As[(ty * 4 + 0) * BKk + w];
      float a1 = As[(ty * 4 + 1) * BKk + w];
      float a2 = As[(ty * 4 + 2) * BKk + w];
      float a3 = As[(ty * 4 + 3) * BKk + w];
      acc[0][0] += a0 * bv.x; acc[0][1] += a0 * bv.y; acc[0][2] += a0 * bv.z; acc[0][3] += a0 * bv.w;
      acc[1][0] += a1 * bv.x; acc[1][1] += a1 * bv.y; acc[1][2] += a1 * bv.z; acc[1][3] += a1 * bv.w;
      acc[2][0] += a2 * bv.x; acc[2][1] += a2 * bv.y; acc[2][2] += a2 * bv.z; acc[2][3] += a2 * bv.w;
      acc[3][0] += a3 * bv.x; acc[3][1] += a3 * bv.y; acc[3][2] += a3 * bv.z; acc[3][3] += a3 * bv.w;
    }
  }
#pragma unroll
  for (int i = 0; i < 4; ++i) {
    int v = v0 + ty * 4 + i;
    if (v < VOCAB) {
      float4 st = make_float4(acc[i][0], acc[i][1], acc[i][2], acc[i][3]);
      *(float4*)&k_ws[(size_t)v * EMBD + n0 + tx * 4] = st;
    }
  }
}

// ---------------- K3: scores + gumbel noise + per-chunk argmax ----------------
// LDS = 52 KB -> 3 blocks/CU = 3 waves/EU; allow up to ~168 VGPRs (no spill).
__global__ __launch_bounds__(256, 3) void score_kernel(
                             const float* __restrict__ q_ws,
                             const float* __restrict__ k_ws,
                             float* __restrict__ pval,
                             int* __restrict__ pidx) {
  __shared__ float Qs[64 * 68];
  __shared__ float Ks[128 * 68];
  const int tid = threadIdx.x;
  const int chunk = blockIdx.x, rowtile = blockIdx.y, h = blockIdx.z;
  const int v0 = chunk * VCHUNK;
  const int ty = tid >> 4, tx = tid & 15;

  for (int f = tid; f < 64 * 16; f += 256) {
    int row = f >> 4, c4 = f & 15;
    *(float4*)&Qs[row * 68 + c4 * 4] =
        *(const float4*)&q_ws[(size_t)(rowtile * 64 + row) * EMBD + h * DHn + c4 * 4];
  }
  for (int f = tid; f < 128 * 16; f += 256) {
    int row = f >> 4, c4 = f & 15;
    int v = v0 + row;
    float4 k4 = (v < VOCAB) ? *(const float4*)&k_ws[(size_t)v * EMBD + h * DHn + c4 * 4]
                            : make_float4(0.f, 0.f, 0.f, 0.f);
    *(float4*)&Ks[row * 68 + c4 * 4] = k4;
  }
  __syncthreads();

  float acc[4][8] = {};
#pragma unroll
  for (int d0 = 0; d0 < DHn; d0 += 4) {
    float4 qf[4], kf[8];
#pragma unroll
    for (int i = 0; i < 4; ++i) qf[i] = *(float4*)&Qs[(ty * 4 + i) * 68 + d0];
#pragma unroll
    for (int j = 0; j < 8; ++j) kf[j] = *(float4*)&Ks[(tx + 16 * j) * 68 + d0];
#pragma unroll
    for (int i = 0; i < 4; ++i)
#pragma unroll
      for (int j = 0; j < 8; ++j)
        acc[i][j] += qf[i].x * kf[j].x + qf[i].y * kf[j].y + qf[i].z * kf[j].z + qf[i].w * kf[j].w;
  }

#pragma unroll
  for (int i = 0; i < 4; ++i) {
    const int r = rowtile * 64 + ty * 4 + i;     // 0..511 within head
    const int b = r >> 7, q = r & 127;
    const uint32_t base = (uint32_t)((b * NH + h) * NQn + q) * (uint32_t)VOCAB;
    float best = -INFINITY; int bidx = 0x7fffffff;
#pragma unroll
    for (int j = 0; j < 8; ++j) {
      int v = v0 + tx + 16 * j;
      if (v < VOCAB) {
        float g = gumbel_ll(base + (uint32_t)v);
        float val = acc[i][j] * 0.125f - g;      // dots*scale - log(-log(u)); TAU=1
        if (val > best || (val == best && v < bidx)) { best = val; bidx = v; }
      }
    }
#pragma unroll
    for (int m = 8; m >= 1; m >>= 1) {
      float ov = __shfl_xor(best, m, 64);
      int   oi = __shfl_xor(bidx, m, 64);
      if (ov > best || (ov == best && oi < bidx)) { best = ov; bidx = oi; }
    }
    if (tx == 0) {
      int prow = h * 512 + r;
      pval[(size_t)prow * NCHUNK + chunk] = best;
      pidx[(size_t)prow * NCHUNK + chunk] = bidx;
    }
  }
}

// ---------------- K4: reduce chunk partials -> final argmax ----------------
__global__ __launch_bounds__(256, 4) void argmax_reduce_kernel(
                                     const float* __restrict__ pval,
                                     const int* __restrict__ pidx,
                                     int* __restrict__ idxf) {
  const int tid = threadIdx.x;
  const int wave = tid >> 6, lane = tid & 63;
  const int row = blockIdx.x * 4 + wave;   // 0..4095 = h*512 + (b*128+q)
  float best = -INFINITY; int bidx = 0x7fffffff;
  for (int c = lane; c < NCHUNK; c += 64) {
    float v = pval[(size_t)row * NCHUNK + c];
    int   i = pidx[(size_t)row * NCHUNK + c];
    if (v > best || (v == best && i < bidx)) { best = v; bidx = i; }
  }
#pragma unroll
  for (int m = 32; m >= 1; m >>= 1) {
    float ov = __shfl_xor(best, m, 64);
    int   oi = __shfl_xor(bidx, m, 64);
    if (ov > best || (ov == best && oi < bidx)) { best = ov; bidx = oi; }
  }
  if (lane == 0) {
    int h = row >> 9, r = row & 511, b = r >> 7, q = r & 127;
    idxf[(b * NH + h) * NQn + q] = bidx;
  }
}

// ---------------- K5: gather + V projection + out proj + residual ----------------
__global__ __launch_bounds__(256, 4) void out_kernel(
                           const float* __restrict__ queries,
                           const float* __restrict__ glove,
                           const float* __restrict__ Wv,
                           const float* __restrict__ Wout,
                           const float* __restrict__ b_out,
                           const int* __restrict__ idxf,
                           float* __restrict__ out) {
  __shared__ float gl[4][NH][WDn];   // 38400 B
  __shared__ float vrow[4][EMBD];    // 8192 B
  __shared__ int idxs[4][NH];
  const int tid = threadIdx.x;
  const int r0 = blockIdx.x * 4;
  if (tid < 32) {
    int rr = tid >> 3, hh = tid & 7;
    int r = r0 + rr, b = r >> 7, q = r & 127;
    idxs[rr][hh] = idxf[(b * NH + hh) * NQn + q];
  }
  __syncthreads();
  for (int f = tid; f < 32 * 75; f += 256) {
    int rp = f / 75, c4 = f % 75;
    int rr = rp >> 3, hh = rp & 7;
    *(float4*)&gl[rr][hh][c4 * 4] = *(const float4*)&glove[(size_t)idxs[rr][hh] * WDn + c4 * 4];
  }
  __syncthreads();
  for (int e = tid; e < EMBD; e += 256) {
    float a0 = 0.f, a1 = 0.f, a2 = 0.f, a3 = 0.f;
    int hh = e >> 6;
    for (int w = 0; w < WDn; ++w) {
      float wv = Wv[(size_t)w * EMBD + e];
      a0 += gl[0][hh][w] * wv; a1 += gl[1][hh][w] * wv;
      a2 += gl[2][hh][w] * wv; a3 += gl[3][hh][w] * wv;
    }
    vrow[0][e] = a0; vrow[1][e] = a1; vrow[2][e] = a2; vrow[3][e] = a3;
  }
  __syncthreads();
  for (int j = tid; j < EMBD; j += 256) {
    float a0 = 0.f, a1 = 0.f, a2 = 0.f, a3 = 0.f;
    for (int e = 0; e < EMBD; ++e) {
      float wo = Wout[(size_t)e * QD + j];
      a0 += vrow[0][e] * wo; a1 += vrow[1][e] * wo;
      a2 += vrow[2][e] * wo; a3 += vrow[3][e] * wo;
    }
    float bb = b_out[j];
    out[(size_t)(r0 + 0) * QD + j] = queries[(size_t)(r0 + 0) * QD + j] + a0 + bb;
    out[(size_t)(r0 + 1) * QD + j] = queries[(size_t)(r0 + 1) * QD + j] + a1 + bb;
    out[(size_t)(r0 + 2) * QD + j] = queries[(size_t)(r0 + 2) * QD + j] + a2 + bb;
    out[(size_t)(r0 + 3) * QD + j] = queries[(size_t)(r0 + 3) * QD + j] + a3 + bb;
  }
}

extern "C" void kernel_launch(void* const* d_in, const int* in_sizes, int n_in,
                              void* d_out, int out_size, void* d_ws, size_t ws_size,
                              hipStream_t stream) {
  const float* queries = (const float*)d_in[0];
  const float* glove   = (const float*)d_in[1];
  const float* Wq      = (const float*)d_in[2];
  const float* Wk      = (const float*)d_in[3];
  const float* Wv      = (const float*)d_in[4];
  const float* Wout    = (const float*)d_in[5];
  const float* b_out   = (const float*)d_in[6];
  const float* ln_g    = (const float*)d_in[7];
  const float* ln_b    = (const float*)d_in[8];
  float* out = (float*)d_out;

  // workspace layout (floats): q[512*512] | k[20000*512] | pval[4096*157] | pidx | idxf
  float* ws   = (float*)d_ws;
  float* q_ws = ws;
  float* k_ws = q_ws + (size_t)NB * NQn * EMBD;
  float* pval = k_ws + (size_t)VOCAB * EMBD;
  int*   pidx = (int*)(pval + (size_t)NH * 512 * NCHUNK);
  int*   idxf = (int*)((float*)pidx + (size_t)NH * 512 * NCHUNK);

  hipLaunchKernelGGL(ln_qproj_kernel, dim3(128), dim3(256), 0, stream,
                     queries, Wq, ln_g, ln_b, q_ws);
  hipLaunchKernelGGL(kproj_kernel, dim3(313, 8), dim3(256), 0, stream,
                     glove, Wk, k_ws);
  hipLaunchKernelGGL(score_kernel, dim3(NCHUNK, 8, NH), dim3(256), 0, stream,
                     q_ws, k_ws, pval, pidx);
  hipLaunchKernelGGL(argmax_reduce_kernel, dim3(1024), dim3(256), 0, stream,
                     pval, pidx, idxf);
  hipLaunchKernelGGL(out_kernel, dim3(128), dim3(256), 0, stream,
                     queries, glove, Wv, Wout, b_out, idxf, out);
}

// Round 3
// 587.473 us; speedup vs baseline: 13.1354x; 12.3087x over previous
//
#include <hip/hip_runtime.h>
#include <cstdint>
#include <cmath>

#define NB 4
#define NQn 128
#define QD 512
#define EMBD 512
#define NH 8
#define DHn 64
#define VOCAB 20000
#define WDn 300
#define VCHUNK 128
#define NCHUNK 157   // ceil(20000/128)

// PRNG variant (verified R1: partitionable threefry, bits = out0 ^ out1)
__device__ __forceinline__ void tf_rounds(uint32_t &x0, uint32_t &x1) {
  const uint32_t ks0 = 0u;
  const uint32_t ks1 = 42u;
  const uint32_t ks2 = 0x1BD11BDAu ^ 42u;
  x0 += ks0; x1 += ks1;
#define TFR(r) { x0 += x1; x1 = (x1 << (r)) | (x1 >> (32 - (r))); x1 ^= x0; }
  TFR(13) TFR(15) TFR(26) TFR(6)  x0 += ks1; x1 += ks2 + 1u;
  TFR(17) TFR(29) TFR(16) TFR(24) x0 += ks2; x1 += ks0 + 2u;
  TFR(13) TFR(15) TFR(26) TFR(6)  x0 += ks0; x1 += ks1 + 3u;
  TFR(17) TFR(29) TFR(16) TFR(24) x0 += ks1; x1 += ks2 + 4u;
  TFR(13) TFR(15) TFR(26) TFR(6)  x0 += ks2; x1 += ks0 + 5u;
#undef TFR
}

__device__ __forceinline__ uint32_t rand_bits(uint32_t l) {
  uint32_t x0 = 0u, x1 = l;
  tf_rounds(x0, x1);
  return x0 ^ x1;
}

// returns log(-log(u)) for element with linear index l (subtract from scaled dots)
__device__ __forceinline__ float gumbel_ll(uint32_t l) {
  uint32_t bits = rand_bits(l);
  float f = __uint_as_float((bits >> 9) | 0x3f800000u) - 1.0f;
  float u = fmaxf(f, 1.17549435e-38f);
  return logf(-logf(u));
}

// ---------------- K1: LayerNorm + Q projection ----------------
__global__ __launch_bounds__(256, 4) void ln_qproj_kernel(
                                const float* __restrict__ queries,
                                const float* __restrict__ Wq,
                                const float* __restrict__ ln_g,
                                const float* __restrict__ ln_b,
                                float* __restrict__ q_ws) {
  __shared__ float xn[4][QD];
  const int tid = threadIdx.x;
  const int wave = tid >> 6, lane = tid & 63;
  const int r = blockIdx.x * 4 + wave;   // global row (b*128+q), 0..511

  float vals[8];
  float s = 0.f;
#pragma unroll
  for (int j = 0; j < 8; ++j) { vals[j] = queries[r * QD + j * 64 + lane]; s += vals[j]; }
#pragma unroll
  for (int m = 32; m >= 1; m >>= 1) s += __shfl_xor(s, m, 64);
  const float mu = s * (1.f / 512.f);
  float ss = 0.f;
#pragma unroll
  for (int j = 0; j < 8; ++j) { float d = vals[j] - mu; ss += d * d; }
#pragma unroll
  for (int m = 32; m >= 1; m >>= 1) ss += __shfl_xor(ss, m, 64);
  const float rstd = 1.f / sqrtf(ss * (1.f / 512.f) + 1e-5f);
#pragma unroll
  for (int j = 0; j < 8; ++j) {
    int e = j * 64 + lane;
    xn[wave][e] = (vals[j] - mu) * rstd * ln_g[e] + ln_b[e];
  }
  __syncthreads();
  for (int e = tid; e < EMBD; e += 256) {
    float a0 = 0.f, a1 = 0.f, a2 = 0.f, a3 = 0.f;
    for (int i = 0; i < QD; ++i) {
      float w = Wq[i * EMBD + e];
      a0 += xn[0][i] * w; a1 += xn[1][i] * w; a2 += xn[2][i] * w; a3 += xn[3][i] * w;
    }
    int r0 = blockIdx.x * 4;
    q_ws[(r0 + 0) * EMBD + e] = a0;
    q_ws[(r0 + 1) * EMBD + e] = a1;
    q_ws[(r0 + 2) * EMBD + e] = a2;
    q_ws[(r0 + 3) * EMBD + e] = a3;
  }
}

// ---------------- K2: k = glove @ Wk (20000 x 300 x 512) ----------------
#define BKk 60
__global__ __launch_bounds__(256, 4) void kproj_kernel(
                             const float* __restrict__ glove,
                             const float* __restrict__ Wk,
                             float* __restrict__ k_ws) {
  __shared__ float As[64 * BKk];      // [row][w], stride 60
  __shared__ float Bs[BKk * 64];      // [w][col]
  const int tid = threadIdx.x;
  const int v0 = blockIdx.x * 64, n0 = blockIdx.y * 64;
  const int ty = tid >> 4, tx = tid & 15;
  float acc[4][4] = {};
  for (int s = 0; s < 5; ++s) {
    const int w0 = s * BKk;
    __syncthreads();
    for (int f = tid; f < 64 * 15; f += 256) {
      int row = f / 15, c4 = f % 15;
      int v = v0 + row;
      float4 g4 = (v < VOCAB) ? *(const float4*)&glove[(size_t)v * WDn + w0 + c4 * 4]
                              : make_float4(0.f, 0.f, 0.f, 0.f);
      *(float4*)&As[row * BKk + c4 * 4] = g4;
    }
    for (int f = tid; f < BKk * 16; f += 256) {
      int row = f / 16, c4 = f % 16;
      *(float4*)&Bs[row * 64 + c4 * 4] = *(const float4*)&Wk[(size_t)(w0 + row) * EMBD + n0 + c4 * 4];
    }
    __syncthreads();
    for (int w = 0; w < BKk; ++w) {
      float4 bv = *(float4*)&Bs[w * 64 + tx * 4];
      float a0 = As[(ty * 4 + 0) * BKk + w];
      float a1 = As[(ty * 4 + 1) * BKk + w];
      float a2 = As[(ty * 4 + 2) * BKk + w];
      float a3 = As[(ty * 4 + 3) * BKk + w];
      acc[0][0] += a0 * bv.x; acc[0][1] += a0 * bv.y; acc[0][2] += a0 * bv.z; acc[0][3] += a0 * bv.w;
      acc[1][0] += a1 * bv.x; acc[1][1] += a1 * bv.y; acc[1][2] += a1 * bv.z; acc[1][3] += a1 * bv.w;
      acc[2][0] += a2 * bv.x; acc[2][1] += a2 * bv.y; acc[2][2] += a2 * bv.z; acc[2][3] += a2 * bv.w;
      acc[3][0] += a3 * bv.x; acc[3][1] += a3 * bv.y; acc[3][2] += a3 * bv.z; acc[3][3] += a3 * bv.w;
    }
  }
#pragma unroll
  for (int i = 0; i < 4; ++i) {
    int v = v0 + ty * 4 + i;
    if (v < VOCAB) {
      float4 st = make_float4(acc[i][0], acc[i][1], acc[i][2], acc[i][3]);
      *(float4*)&k_ws[(size_t)v * EMBD + n0 + tx * 4] = st;
    }
  }
}

// ---------------- K3: scores + gumbel noise + per-chunk argmax ----------------
// Register-pressure-safe inner loop: named float4 temporaries only (no staged
// arrays that can spill). Peak live ~ acc(32) + k0..k7(32) + qv(4) + addr.
__global__ __launch_bounds__(256, 2) void score_kernel(
                             const float* __restrict__ q_ws,
                             const float* __restrict__ k_ws,
                             float* __restrict__ pval,
                             int* __restrict__ pidx) {
  __shared__ float Qs[64 * 68];
  __shared__ float Ks[128 * 68];
  const int tid = threadIdx.x;
  const int chunk = blockIdx.x, rowtile = blockIdx.y, h = blockIdx.z;
  const int v0 = chunk * VCHUNK;
  const int ty = tid >> 4, tx = tid & 15;

  for (int f = tid; f < 64 * 16; f += 256) {
    int row = f >> 4, c4 = f & 15;
    *(float4*)&Qs[row * 68 + c4 * 4] =
        *(const float4*)&q_ws[(size_t)(rowtile * 64 + row) * EMBD + h * DHn + c4 * 4];
  }
  for (int f = tid; f < 128 * 16; f += 256) {
    int row = f >> 4, c4 = f & 15;
    int v = v0 + row;
    float4 k4 = (v < VOCAB) ? *(const float4*)&k_ws[(size_t)v * EMBD + h * DHn + c4 * 4]
                            : make_float4(0.f, 0.f, 0.f, 0.f);
    *(float4*)&Ks[row * 68 + c4 * 4] = k4;
  }
  __syncthreads();

  float acc[4][8] = {};
  for (int d0 = 0; d0 < DHn; d0 += 4) {   // rolled: short live ranges
    const float* kb = &Ks[tx * 68 + d0];
    float4 k0 = *(const float4*)(kb + 0 * 16 * 68);
    float4 k1 = *(const float4*)(kb + 1 * 16 * 68);
    float4 k2 = *(const float4*)(kb + 2 * 16 * 68);
    float4 k3 = *(const float4*)(kb + 3 * 16 * 68);
    float4 k4 = *(const float4*)(kb + 4 * 16 * 68);
    float4 k5 = *(const float4*)(kb + 5 * 16 * 68);
    float4 k6 = *(const float4*)(kb + 6 * 16 * 68);
    float4 k7 = *(const float4*)(kb + 7 * 16 * 68);
#pragma unroll
    for (int i = 0; i < 4; ++i) {
      float4 qv = *(const float4*)&Qs[(ty * 4 + i) * 68 + d0];
      acc[i][0] += qv.x * k0.x + qv.y * k0.y + qv.z * k0.z + qv.w * k0.w;
      acc[i][1] += qv.x * k1.x + qv.y * k1.y + qv.z * k1.z + qv.w * k1.w;
      acc[i][2] += qv.x * k2.x + qv.y * k2.y + qv.z * k2.z + qv.w * k2.w;
      acc[i][3] += qv.x * k3.x + qv.y * k3.y + qv.z * k3.z + qv.w * k3.w;
      acc[i][4] += qv.x * k4.x + qv.y * k4.y + qv.z * k4.z + qv.w * k4.w;
      acc[i][5] += qv.x * k5.x + qv.y * k5.y + qv.z * k5.z + qv.w * k5.w;
      acc[i][6] += qv.x * k6.x + qv.y * k6.y + qv.z * k6.z + qv.w * k6.w;
      acc[i][7] += qv.x * k7.x + qv.y * k7.y + qv.z * k7.z + qv.w * k7.w;
    }
  }

#pragma unroll
  for (int i = 0; i < 4; ++i) {
    const int r = rowtile * 64 + ty * 4 + i;     // 0..511 within head
    const int b = r >> 7, q = r & 127;
    const uint32_t base = (uint32_t)((b * NH + h) * NQn + q) * (uint32_t)VOCAB;
    float best = -INFINITY; int bidx = 0x7fffffff;
#pragma unroll
    for (int j = 0; j < 8; ++j) {
      int v = v0 + tx + 16 * j;
      if (v < VOCAB) {
        float g = gumbel_ll(base + (uint32_t)v);
        float val = acc[i][j] * 0.125f - g;      // dots*scale - log(-log(u)); TAU=1
        if (val > best || (val == best && v < bidx)) { best = val; bidx = v; }
      }
    }
#pragma unroll
    for (int m = 8; m >= 1; m >>= 1) {
      float ov = __shfl_xor(best, m, 64);
      int   oi = __shfl_xor(bidx, m, 64);
      if (ov > best || (ov == best && oi < bidx)) { best = ov; bidx = oi; }
    }
    if (tx == 0) {
      int prow = h * 512 + r;
      pval[(size_t)prow * NCHUNK + chunk] = best;
      pidx[(size_t)prow * NCHUNK + chunk] = bidx;
    }
  }
}

// ---------------- K4: reduce chunk partials -> final argmax ----------------
__global__ __launch_bounds__(256, 4) void argmax_reduce_kernel(
                                     const float* __restrict__ pval,
                                     const int* __restrict__ pidx,
                                     int* __restrict__ idxf) {
  const int tid = threadIdx.x;
  const int wave = tid >> 6, lane = tid & 63;
  const int row = blockIdx.x * 4 + wave;   // 0..4095 = h*512 + (b*128+q)
  float best = -INFINITY; int bidx = 0x7fffffff;
  for (int c = lane; c < NCHUNK; c += 64) {
    float v = pval[(size_t)row * NCHUNK + c];
    int   i = pidx[(size_t)row * NCHUNK + c];
    if (v > best || (v == best && i < bidx)) { best = v; bidx = i; }
  }
#pragma unroll
  for (int m = 32; m >= 1; m >>= 1) {
    float ov = __shfl_xor(best, m, 64);
    int   oi = __shfl_xor(bidx, m, 64);
    if (ov > best || (ov == best && oi < bidx)) { best = ov; bidx = oi; }
  }
  if (lane == 0) {
    int h = row >> 9, r = row & 511, b = r >> 7, q = r & 127;
    idxf[(b * NH + h) * NQn + q] = bidx;
  }
}

// ---------------- K5: gather + V projection + out proj + residual ----------------
__global__ __launch_bounds__(256, 4) void out_kernel(
                           const float* __restrict__ queries,
                           const float* __restrict__ glove,
                           const float* __restrict__ Wv,
                           const float* __restrict__ Wout,
                           const float* __restrict__ b_out,
                           const int* __restrict__ idxf,
                           float* __restrict__ out) {
  __shared__ float gl[4][NH][WDn];   // 38400 B
  __shared__ float vrow[4][EMBD];    // 8192 B
  __shared__ int idxs[4][NH];
  const int tid = threadIdx.x;
  const int r0 = blockIdx.x * 4;
  if (tid < 32) {
    int rr = tid >> 3, hh = tid & 7;
    int r = r0 + rr, b = r >> 7, q = r & 127;
    idxs[rr][hh] = idxf[(b * NH + hh) * NQn + q];
  }
  __syncthreads();
  for (int f = tid; f < 32 * 75; f += 256) {
    int rp = f / 75, c4 = f % 75;
    int rr = rp >> 3, hh = rp & 7;
    *(float4*)&gl[rr][hh][c4 * 4] = *(const float4*)&glove[(size_t)idxs[rr][hh] * WDn + c4 * 4];
  }
  __syncthreads();
  for (int e = tid; e < EMBD; e += 256) {
    float a0 = 0.f, a1 = 0.f, a2 = 0.f, a3 = 0.f;
    int hh = e >> 6;
    for (int w = 0; w < WDn; ++w) {
      float wv = Wv[(size_t)w * EMBD + e];
      a0 += gl[0][hh][w] * wv; a1 += gl[1][hh][w] * wv;
      a2 += gl[2][hh][w] * wv; a3 += gl[3][hh][w] * wv;
    }
    vrow[0][e] = a0; vrow[1][e] = a1; vrow[2][e] = a2; vrow[3][e] = a3;
  }
  __syncthreads();
  for (int j = tid; j < EMBD; j += 256) {
    float a0 = 0.f, a1 = 0.f, a2 = 0.f, a3 = 0.f;
    for (int e = 0; e < EMBD; ++e) {
      float wo = Wout[(size_t)e * QD + j];
      a0 += vrow[0][e] * wo; a1 += vrow[1][e] * wo;
      a2 += vrow[2][e] * wo; a3 += vrow[3][e] * wo;
    }
    float bb = b_out[j];
    out[(size_t)(r0 + 0) * QD + j] = queries[(size_t)(r0 + 0) * QD + j] + a0 + bb;
    out[(size_t)(r0 + 1) * QD + j] = queries[(size_t)(r0 + 1) * QD + j] + a1 + bb;
    out[(size_t)(r0 + 2) * QD + j] = queries[(size_t)(r0 + 2) * QD + j] + a2 + bb;
    out[(size_t)(r0 + 3) * QD + j] = queries[(size_t)(r0 + 3) * QD + j] + a3 + bb;
  }
}

extern "C" void kernel_launch(void* const* d_in, const int* in_sizes, int n_in,
                              void* d_out, int out_size, void* d_ws, size_t ws_size,
                              hipStream_t stream) {
  const float* queries = (const float*)d_in[0];
  const float* glove   = (const float*)d_in[1];
  const float* Wq      = (const float*)d_in[2];
  const float* Wk      = (const float*)d_in[3];
  const float* Wv      = (const float*)d_in[4];
  const float* Wout    = (const float*)d_in[5];
  const float* b_out   = (const float*)d_in[6];
  const float* ln_g    = (const float*)d_in[7];
  const float* ln_b    = (const float*)d_in[8];
  float* out = (float*)d_out;

  // workspace layout (floats): q[512*512] | k[20000*512] | pval[4096*157] | pidx | idxf
  float* ws   = (float*)d_ws;
  float* q_ws = ws;
  float* k_ws = q_ws + (size_t)NB * NQn * EMBD;
  float* pval = k_ws + (size_t)VOCAB * EMBD;
  int*   pidx = (int*)(pval + (size_t)NH * 512 * NCHUNK);
  int*   idxf = (int*)((float*)pidx + (size_t)NH * 512 * NCHUNK);

  hipLaunchKernelGGL(ln_qproj_kernel, dim3(128), dim3(256), 0, stream,
                     queries, Wq, ln_g, ln_b, q_ws);
  hipLaunchKernelGGL(kproj_kernel, dim3(313, 8), dim3(256), 0, stream,
                     glove, Wk, k_ws);
  hipLaunchKernelGGL(score_kernel, dim3(NCHUNK, 8, NH), dim3(256), 0, stream,
                     q_ws, k_ws, pval, pidx);
  hipLaunchKernelGGL(argmax_reduce_kernel, dim3(1024), dim3(256), 0, stream,
                     pval, pidx, idxf);
  hipLaunchKernelGGL(out_kernel, dim3(128), dim3(256), 0, stream,
                     queries, glove, Wv, Wout, b_out, idxf, out);
}

// Round 4
// 543.408 us; speedup vs baseline: 14.2005x; 1.0811x over previous
//
#include <hip/hip_runtime.h>
#include <cstdint>
#include <cmath>

#define NB 4
#define NQn 128
#define QD 512
#define EMBD 512
#define NH 8
#define DHn 64
#define VOCAB 20000
#define WDn 300
#define VCHUNK 128
#define NCHUNK 157   // ceil(20000/128)

typedef float f32x4 __attribute__((ext_vector_type(4)));
typedef float f32x2 __attribute__((ext_vector_type(2)));

__device__ __forceinline__ f32x2 lo2(f32x4 v) { return __builtin_shufflevector(v, v, 0, 1); }
__device__ __forceinline__ f32x2 hi2(f32x4 v) { return __builtin_shufflevector(v, v, 2, 3); }

// d += a * b per 32-bit half (v_pk_fma_f32, full-rate packed fp32 on CDNA2+)
__device__ __forceinline__ void pk_fma(f32x2 &d, f32x2 a, f32x2 b) {
  asm("v_pk_fma_f32 %0, %1, %2, %0" : "+v"(d) : "v"(a), "v"(b));
}

// PRNG (verified R1: partitionable threefry2x32, key=(0,42), bits = out0 ^ out1)
__device__ __forceinline__ void tf_rounds(uint32_t &x0, uint32_t &x1) {
  const uint32_t ks0 = 0u;
  const uint32_t ks1 = 42u;
  const uint32_t ks2 = 0x1BD11BDAu ^ 42u;
  x0 += ks0; x1 += ks1;
#define TFR(r) { x0 += x1; x1 = (x1 << (r)) | (x1 >> (32 - (r))); x1 ^= x0; }
  TFR(13) TFR(15) TFR(26) TFR(6)  x0 += ks1; x1 += ks2 + 1u;
  TFR(17) TFR(29) TFR(16) TFR(24) x0 += ks2; x1 += ks0 + 2u;
  TFR(13) TFR(15) TFR(26) TFR(6)  x0 += ks0; x1 += ks1 + 3u;
  TFR(17) TFR(29) TFR(16) TFR(24) x0 += ks1; x1 += ks2 + 4u;
  TFR(13) TFR(15) TFR(26) TFR(6)  x0 += ks2; x1 += ks0 + 5u;
#undef TFR
}

__device__ __forceinline__ float gumbel_ll(uint32_t l) {
  uint32_t x0 = 0u, x1 = l;
  tf_rounds(x0, x1);
  uint32_t bits = x0 ^ x1;
  float f = __uint_as_float((bits >> 9) | 0x3f800000u) - 1.0f;
  float u = fmaxf(f, 1.17549435e-38f);
  return logf(-logf(u));
}

// ---------------- K1: LayerNorm + Q projection ----------------
// grid (128, 2): x = 4-row group, y = 256-col half. xn stored transposed so one
// broadcast ds_read_b128 per i feeds all 4 row-FMAs.
__global__ __launch_bounds__(256, 4) void ln_qproj_kernel(
                                const float* __restrict__ queries,
                                const float* __restrict__ Wq,
                                const float* __restrict__ ln_g,
                                const float* __restrict__ ln_b,
                                float* __restrict__ q_ws) {
  __shared__ float xnT[QD][4];   // [i][row], 8 KB
  const int tid = threadIdx.x;
  const int wave = tid >> 6, lane = tid & 63;
  const int r0 = blockIdx.x * 4;
  const int r = r0 + wave;

  float vals[8];
  float s = 0.f;
#pragma unroll
  for (int j = 0; j < 8; ++j) { vals[j] = queries[r * QD + j * 64 + lane]; s += vals[j]; }
#pragma unroll
  for (int m = 32; m >= 1; m >>= 1) s += __shfl_xor(s, m, 64);
  const float mu = s * (1.f / 512.f);
  float ss = 0.f;
#pragma unroll
  for (int j = 0; j < 8; ++j) { float d = vals[j] - mu; ss += d * d; }
#pragma unroll
  for (int m = 32; m >= 1; m >>= 1) ss += __shfl_xor(ss, m, 64);
  const float rstd = 1.f / sqrtf(ss * (1.f / 512.f) + 1e-5f);
#pragma unroll
  for (int j = 0; j < 8; ++j) {
    int e = j * 64 + lane;
    xnT[e][wave] = (vals[j] - mu) * rstd * ln_g[e] + ln_b[e];
  }
  __syncthreads();

  const int e = blockIdx.y * 256 + tid;   // one output column per thread
  float a0 = 0.f, a1 = 0.f, a2 = 0.f, a3 = 0.f;
#pragma unroll 4
  for (int i = 0; i < QD; ++i) {
    f32x4 xv = *(const f32x4*)&xnT[i][0];   // same addr all lanes -> LDS broadcast
    float w = Wq[i * EMBD + e];
    a0 += xv.x * w; a1 += xv.y * w; a2 += xv.z * w; a3 += xv.w * w;
  }
  q_ws[(r0 + 0) * EMBD + e] = a0;
  q_ws[(r0 + 1) * EMBD + e] = a1;
  q_ws[(r0 + 2) * EMBD + e] = a2;
  q_ws[(r0 + 3) * EMBD + e] = a3;
}

// ---------------- K2: k = glove @ Wk (20000 x 300 x 512) ----------------
#define BKk 60
__global__ __launch_bounds__(256, 4) void kproj_kernel(
                             const float* __restrict__ glove,
                             const float* __restrict__ Wk,
                             float* __restrict__ k_ws) {
  __shared__ float As[64 * BKk];      // [row][w], stride 60
  __shared__ float Bs[BKk * 64];      // [w][col]
  const int tid = threadIdx.x;
  const int v0 = blockIdx.x * 64, n0 = blockIdx.y * 64;
  const int ty = tid >> 4, tx = tid & 15;
  float acc[4][4] = {};
  for (int s = 0; s < 5; ++s) {
    const int w0 = s * BKk;
    __syncthreads();
    for (int f = tid; f < 64 * 15; f += 256) {
      int row = f / 15, c4 = f % 15;
      int v = v0 + row;
      float4 g4 = (v < VOCAB) ? *(const float4*)&glove[(size_t)v * WDn + w0 + c4 * 4]
                              : make_float4(0.f, 0.f, 0.f, 0.f);
      *(float4*)&As[row * BKk + c4 * 4] = g4;
    }
    for (int f = tid; f < BKk * 16; f += 256) {
      int row = f / 16, c4 = f % 16;
      *(float4*)&Bs[row * 64 + c4 * 4] = *(const float4*)&Wk[(size_t)(w0 + row) * EMBD + n0 + c4 * 4];
    }
    __syncthreads();
    for (int w = 0; w < BKk; ++w) {
      float4 bv = *(float4*)&Bs[w * 64 + tx * 4];
      float a0 = As[(ty * 4 + 0) * BKk + w];
      float a1 = As[(ty * 4 + 1) * BKk + w];
      float a2 = As[(ty * 4 + 2) * BKk + w];
      float a3 = As[(ty * 4 + 3) * BKk + w];
      acc[0][0] += a0 * bv.x; acc[0][1] += a0 * bv.y; acc[0][2] += a0 * bv.z; acc[0][3] += a0 * bv.w;
      acc[1][0] += a1 * bv.x; acc[1][1] += a1 * bv.y; acc[1][2] += a1 * bv.z; acc[1][3] += a1 * bv.w;
      acc[2][0] += a2 * bv.x; acc[2][1] += a2 * bv.y; acc[2][2] += a2 * bv.z; acc[2][3] += a2 * bv.w;
      acc[3][0] += a3 * bv.x; acc[3][1] += a3 * bv.y; acc[3][2] += a3 * bv.z; acc[3][3] += a3 * bv.w;
    }
  }
#pragma unroll
  for (int i = 0; i < 4; ++i) {
    int v = v0 + ty * 4 + i;
    if (v < VOCAB) {
      float4 st = make_float4(acc[i][0], acc[i][1], acc[i][2], acc[i][3]);
      *(float4*)&k_ws[(size_t)v * EMBD + n0 + tx * 4] = st;
    }
  }
}

// ---------------- K3: scores + gumbel noise + per-chunk argmax ----------------
template<bool FULL>
__device__ __forceinline__ void score_epi(const f32x2 (&acc)[4][8],
                                          int v0, int tx, int ty, int rowtile, int h,
                                          int chunk, float* __restrict__ pval,
                                          int* __restrict__ pidx) {
#pragma unroll
  for (int i = 0; i < 4; ++i) {
    const int r = rowtile * 64 + ty * 4 + i;     // 0..511 within head
    const int b = r >> 7, q = r & 127;
    const uint32_t base = (uint32_t)((b * NH + h) * NQn + q) * (uint32_t)VOCAB;
    float best = -INFINITY; int bidx = 0x7fffffff;
#pragma unroll
    for (int j = 0; j < 8; ++j) {
      int v = v0 + tx + 16 * j;
      if (FULL || v < VOCAB) {
        float g = gumbel_ll(base + (uint32_t)v);
        float val = (acc[i][j].x + acc[i][j].y) - g;   // q pre-scaled by 0.125 (exact)
        if (val > best || (val == best && v < bidx)) { best = val; bidx = v; }
      }
    }
#pragma unroll
    for (int m = 8; m >= 1; m >>= 1) {
      float ov = __shfl_xor(best, m, 64);
      int   oi = __shfl_xor(bidx, m, 64);
      if (ov > best || (ov == best && oi < bidx)) { best = ov; bidx = oi; }
    }
    if (tx == 0) {
      int prow = h * 512 + r;
      pval[(size_t)prow * NCHUNK + chunk] = best;
      pidx[(size_t)prow * NCHUNK + chunk] = bidx;
    }
  }
}

__global__ __launch_bounds__(256, 2) void score_kernel(
                             const float* __restrict__ q_ws,
                             const float* __restrict__ k_ws,
                             float* __restrict__ pval,
                             int* __restrict__ pidx) {
  __shared__ float Qs[64 * 68];
  __shared__ float Ks[128 * 68];
  const int tid = threadIdx.x;
  const int chunk = blockIdx.x, rowtile = blockIdx.y, h = blockIdx.z;
  const int v0 = chunk * VCHUNK;
  const int ty = tid >> 4, tx = tid & 15;

  for (int f = tid; f < 64 * 16; f += 256) {
    int row = f >> 4, c4 = f & 15;
    f32x4 qv = *(const f32x4*)&q_ws[(size_t)(rowtile * 64 + row) * EMBD + h * DHn + c4 * 4];
    qv *= 0.125f;                                    // fold scale (2^-3, exact)
    *(f32x4*)&Qs[row * 68 + c4 * 4] = qv;
  }
  for (int f = tid; f < 128 * 16; f += 256) {
    int row = f >> 4, c4 = f & 15;
    int v = v0 + row;
    f32x4 k4 = {0.f, 0.f, 0.f, 0.f};
    if (v < VOCAB) k4 = *(const f32x4*)&k_ws[(size_t)v * EMBD + h * DHn + c4 * 4];
    *(f32x4*)&Ks[row * 68 + c4 * 4] = k4;
  }
  __syncthreads();

  f32x2 acc[4][8] = {};
#pragma unroll 1
  for (int d0 = 0; d0 < DHn; d0 += 4) {
    const float* kb = &Ks[tx * 68 + d0];
    f32x4 k0 = *(const f32x4*)(kb + 0 * 16 * 68);
    f32x4 k1 = *(const f32x4*)(kb + 1 * 16 * 68);
    f32x4 k2 = *(const f32x4*)(kb + 2 * 16 * 68);
    f32x4 k3 = *(const f32x4*)(kb + 3 * 16 * 68);
    f32x4 k4 = *(const f32x4*)(kb + 4 * 16 * 68);
    f32x4 k5 = *(const f32x4*)(kb + 5 * 16 * 68);
    f32x4 k6 = *(const f32x4*)(kb + 6 * 16 * 68);
    f32x4 k7 = *(const f32x4*)(kb + 7 * 16 * 68);
#pragma unroll
    for (int i = 0; i < 4; ++i) {
      f32x4 qv = *(const f32x4*)&Qs[(ty * 4 + i) * 68 + d0];
      f32x2 ql = lo2(qv), qh = hi2(qv);
      pk_fma(acc[i][0], ql, lo2(k0)); pk_fma(acc[i][0], qh, hi2(k0));
      pk_fma(acc[i][1], ql, lo2(k1)); pk_fma(acc[i][1], qh, hi2(k1));
      pk_fma(acc[i][2], ql, lo2(k2)); pk_fma(acc[i][2], qh, hi2(k2));
      pk_fma(acc[i][3], ql, lo2(k3)); pk_fma(acc[i][3], qh, hi2(k3));
      pk_fma(acc[i][4], ql, lo2(k4)); pk_fma(acc[i][4], qh, hi2(k4));
      pk_fma(acc[i][5], ql, lo2(k5)); pk_fma(acc[i][5], qh, hi2(k5));
      pk_fma(acc[i][6], ql, lo2(k6)); pk_fma(acc[i][6], qh, hi2(k6));
      pk_fma(acc[i][7], ql, lo2(k7)); pk_fma(acc[i][7], qh, hi2(k7));
    }
  }

  if (v0 + VCHUNK <= VOCAB)
    score_epi<true>(acc, v0, tx, ty, rowtile, h, chunk, pval, pidx);
  else
    score_epi<false>(acc, v0, tx, ty, rowtile, h, chunk, pval, pidx);
}

// ---------------- K4: reduce chunk partials -> final argmax ----------------
__global__ __launch_bounds__(256, 4) void argmax_reduce_kernel(
                                     const float* __restrict__ pval,
                                     const int* __restrict__ pidx,
                                     int* __restrict__ idxf) {
  const int tid = threadIdx.x;
  const int wave = tid >> 6, lane = tid & 63;
  const int row = blockIdx.x * 4 + wave;   // 0..4095 = h*512 + (b*128+q)
  float best = -INFINITY; int bidx = 0x7fffffff;
  for (int c = lane; c < NCHUNK; c += 64) {
    float v = pval[(size_t)row * NCHUNK + c];
    int   i = pidx[(size_t)row * NCHUNK + c];
    if (v > best || (v == best && i < bidx)) { best = v; bidx = i; }
  }
#pragma unroll
  for (int m = 32; m >= 1; m >>= 1) {
    float ov = __shfl_xor(best, m, 64);
    int   oi = __shfl_xor(bidx, m, 64);
    if (ov > best || (ov == best && oi < bidx)) { best = ov; bidx = oi; }
  }
  if (lane == 0) {
    int h = row >> 9, r = row & 511, b = r >> 7, q = r & 127;
    idxf[(b * NH + h) * NQn + q] = bidx;
  }
}

// ---------------- K5: gather + V projection + out proj + residual ----------------
__global__ __launch_bounds__(256, 4) void out_kernel(
                           const float* __restrict__ queries,
                           const float* __restrict__ glove,
                           const float* __restrict__ Wv,
                           const float* __restrict__ Wout,
                           const float* __restrict__ b_out,
                           const int* __restrict__ idxf,
                           float* __restrict__ out) {
  __shared__ float gl[4][NH][WDn];   // 38400 B
  __shared__ float vrow[4][EMBD];    // 8192 B
  __shared__ int idxs[4][NH];
  const int tid = threadIdx.x;
  const int r0 = blockIdx.x * 4;
  if (tid < 32) {
    int rr = tid >> 3, hh = tid & 7;
    int r = r0 + rr, b = r >> 7, q = r & 127;
    idxs[rr][hh] = idxf[(b * NH + hh) * NQn + q];
  }
  __syncthreads();
  for (int f = tid; f < 32 * 75; f += 256) {
    int rp = f / 75, c4 = f % 75;
    int rr = rp >> 3, hh = rp & 7;
    *(float4*)&gl[rr][hh][c4 * 4] = *(const float4*)&glove[(size_t)idxs[rr][hh] * WDn + c4 * 4];
  }
  __syncthreads();
  for (int e = tid; e < EMBD; e += 256) {
    float a0 = 0.f, a1 = 0.f, a2 = 0.f, a3 = 0.f;
    int hh = e >> 6;
    for (int w = 0; w < WDn; ++w) {
      float wv = Wv[(size_t)w * EMBD + e];
      a0 += gl[0][hh][w] * wv; a1 += gl[1][hh][w] * wv;
      a2 += gl[2][hh][w] * wv; a3 += gl[3][hh][w] * wv;
    }
    vrow[0][e] = a0; vrow[1][e] = a1; vrow[2][e] = a2; vrow[3][e] = a3;
  }
  __syncthreads();
  for (int j = tid; j < EMBD; j += 256) {
    float a0 = 0.f, a1 = 0.f, a2 = 0.f, a3 = 0.f;
    for (int e = 0; e < EMBD; ++e) {
      float wo = Wout[(size_t)e * QD + j];
      a0 += vrow[0][e] * wo; a1 += vrow[1][e] * wo;
      a2 += vrow[2][e] * wo; a3 += vrow[3][e] * wo;
    }
    float bb = b_out[j];
    out[(size_t)(r0 + 0) * QD + j] = queries[(size_t)(r0 + 0) * QD + j] + a0 + bb;
    out[(size_t)(r0 + 1) * QD + j] = queries[(size_t)(r0 + 1) * QD + j] + a1 + bb;
    out[(size_t)(r0 + 2) * QD + j] = queries[(size_t)(r0 + 2) * QD + j] + a2 + bb;
    out[(size_t)(r0 + 3) * QD + j] = queries[(size_t)(r0 + 3) * QD + j] + a3 + bb;
  }
}

extern "C" void kernel_launch(void* const* d_in, const int* in_sizes, int n_in,
                              void* d_out, int out_size, void* d_ws, size_t ws_size,
                              hipStream_t stream) {
  const float* queries = (const float*)d_in[0];
  const float* glove   = (const float*)d_in[1];
  const float* Wq      = (const float*)d_in[2];
  const float* Wk      = (const float*)d_in[3];
  const float* Wv      = (const float*)d_in[4];
  const float* Wout    = (const float*)d_in[5];
  const float* b_out   = (const float*)d_in[6];
  const float* ln_g    = (const float*)d_in[7];
  const float* ln_b    = (const float*)d_in[8];
  float* out = (float*)d_out;

  // workspace layout (floats): q[512*512] | k[20000*512] | pval[4096*157] | pidx | idxf
  float* ws   = (float*)d_ws;
  float* q_ws = ws;
  float* k_ws = q_ws + (size_t)NB * NQn * EMBD;
  float* pval = k_ws + (size_t)VOCAB * EMBD;
  int*   pidx = (int*)(pval + (size_t)NH * 512 * NCHUNK);
  int*   idxf = (int*)((float*)pidx + (size_t)NH * 512 * NCHUNK);

  hipLaunchKernelGGL(ln_qproj_kernel, dim3(128, 2), dim3(256), 0, stream,
                     queries, Wq, ln_g, ln_b, q_ws);
  hipLaunchKernelGGL(kproj_kernel, dim3(313, 8), dim3(256), 0, stream,
                     glove, Wk, k_ws);
  hipLaunchKernelGGL(score_kernel, dim3(NCHUNK, 8, NH), dim3(256), 0, stream,
                     q_ws, k_ws, pval, pidx);
  hipLaunchKernelGGL(argmax_reduce_kernel, dim3(1024), dim3(256), 0, stream,
                     pval, pidx, idxf);
  hipLaunchKernelGGL(out_kernel, dim3(128), dim3(256), 0, stream,
                     queries, glove, Wv, Wout, b_out, idxf, out);
}

// Round 5
// 518.436 us; speedup vs baseline: 14.8845x; 1.0482x over previous
//
#include <hip/hip_runtime.h>
#include <cstdint>
#include <cmath>

#define NB 4
#define NQn 128
#define QD 512
#define EMBD 512
#define NH 8
#define DHn 64
#define VOCAB 20000
#define WDn 300
#define VCHUNK 128
#define NCHUNK 157   // ceil(20000/128)

typedef float f32x4 __attribute__((ext_vector_type(4)));
typedef float f32x2 __attribute__((ext_vector_type(2)));

__device__ __forceinline__ f32x2 lo2(f32x4 v) { return __builtin_shufflevector(v, v, 0, 1); }
__device__ __forceinline__ f32x2 hi2(f32x4 v) { return __builtin_shufflevector(v, v, 2, 3); }

// d += a * b per 32-bit half (v_pk_fma_f32, full-rate packed fp32 on CDNA2+)
__device__ __forceinline__ void pk_fma(f32x2 &d, f32x2 a, f32x2 b) {
  asm("v_pk_fma_f32 %0, %1, %2, %0" : "+v"(d) : "v"(a), "v"(b));
}
// d += a.lo * b  (broadcast lo half of a to both lanes) — bitwise == 2x v_fmac
__device__ __forceinline__ void pk_fma_blo(f32x2 &d, f32x2 a, f32x2 b) {
  asm("v_pk_fma_f32 %0, %1, %2, %0 op_sel:[0,0,0] op_sel_hi:[0,1,1]"
      : "+v"(d) : "v"(a), "v"(b));
}
// d += a.hi * b  (broadcast hi half of a to both lanes)
__device__ __forceinline__ void pk_fma_bhi(f32x2 &d, f32x2 a, f32x2 b) {
  asm("v_pk_fma_f32 %0, %1, %2, %0 op_sel:[1,0,0] op_sel_hi:[1,1,1]"
      : "+v"(d) : "v"(a), "v"(b));
}

// PRNG (verified R1: partitionable threefry2x32, key=(0,42), bits = out0 ^ out1)
__device__ __forceinline__ void tf_rounds(uint32_t &x0, uint32_t &x1) {
  const uint32_t ks0 = 0u;
  const uint32_t ks1 = 42u;
  const uint32_t ks2 = 0x1BD11BDAu ^ 42u;
  x0 += ks0; x1 += ks1;
#define TFR(r) { x0 += x1; x1 = (x1 << (r)) | (x1 >> (32 - (r))); x1 ^= x0; }
  TFR(13) TFR(15) TFR(26) TFR(6)  x0 += ks1; x1 += ks2 + 1u;
  TFR(17) TFR(29) TFR(16) TFR(24) x0 += ks2; x1 += ks0 + 2u;
  TFR(13) TFR(15) TFR(26) TFR(6)  x0 += ks0; x1 += ks1 + 3u;
  TFR(17) TFR(29) TFR(16) TFR(24) x0 += ks1; x1 += ks2 + 4u;
  TFR(13) TFR(15) TFR(26) TFR(6)  x0 += ks2; x1 += ks0 + 5u;
#undef TFR
}

// log(-log(u)) via hardware log2: L=-log2(u); ln(L*ln2) = ln2*log2(L) + ln(ln2)
__device__ __forceinline__ float gumbel_ll(uint32_t l) {
  uint32_t x0 = 0u, x1 = l;
  tf_rounds(x0, x1);
  uint32_t bits = x0 ^ x1;
  float f = __uint_as_float((bits >> 9) | 0x3f800000u) - 1.0f;
  float u = fmaxf(f, 1.17549435e-38f);
  float t = __log2f(u);            // log2(u) in [-126.2, -1.7e-7]
  float s = __log2f(-t);           // log2(-log2(u))
  return fmaf(0.69314718f, s, -0.36651292f);
}

// ---------------- K1: LayerNorm + Q projection ----------------
__global__ __launch_bounds__(256, 4) void ln_qproj_kernel(
                                const float* __restrict__ queries,
                                const float* __restrict__ Wq,
                                const float* __restrict__ ln_g,
                                const float* __restrict__ ln_b,
                                float* __restrict__ q_ws) {
  __shared__ float xnT[QD][4];   // [i][row], 8 KB
  const int tid = threadIdx.x;
  const int wave = tid >> 6, lane = tid & 63;
  const int r0 = blockIdx.x * 4;
  const int r = r0 + wave;

  float vals[8];
  float s = 0.f;
#pragma unroll
  for (int j = 0; j < 8; ++j) { vals[j] = queries[r * QD + j * 64 + lane]; s += vals[j]; }
#pragma unroll
  for (int m = 32; m >= 1; m >>= 1) s += __shfl_xor(s, m, 64);
  const float mu = s * (1.f / 512.f);
  float ss = 0.f;
#pragma unroll
  for (int j = 0; j < 8; ++j) { float d = vals[j] - mu; ss += d * d; }
#pragma unroll
  for (int m = 32; m >= 1; m >>= 1) ss += __shfl_xor(ss, m, 64);
  const float rstd = 1.f / sqrtf(ss * (1.f / 512.f) + 1e-5f);
#pragma unroll
  for (int j = 0; j < 8; ++j) {
    int e = j * 64 + lane;
    xnT[e][wave] = (vals[j] - mu) * rstd * ln_g[e] + ln_b[e];
  }
  __syncthreads();

  const int e = blockIdx.y * 256 + tid;   // one output column per thread
  float a0 = 0.f, a1 = 0.f, a2 = 0.f, a3 = 0.f;
#pragma unroll 4
  for (int i = 0; i < QD; ++i) {
    f32x4 xv = *(const f32x4*)&xnT[i][0];   // same addr all lanes -> LDS broadcast
    float w = Wq[i * EMBD + e];
    a0 += xv.x * w; a1 += xv.y * w; a2 += xv.z * w; a3 += xv.w * w;
  }
  q_ws[(r0 + 0) * EMBD + e] = a0;
  q_ws[(r0 + 1) * EMBD + e] = a1;
  q_ws[(r0 + 2) * EMBD + e] = a2;
  q_ws[(r0 + 3) * EMBD + e] = a3;
}

// ---------------- K2: k = glove @ Wk (20000 x 300 x 512) ----------------
// pk_fma with op_sel broadcast: same per-accumulator w-order as scalar fma,
// bitwise-identical results, half the FMA instruction count.
#define BKk 60
__global__ __launch_bounds__(256, 4) void kproj_kernel(
                             const float* __restrict__ glove,
                             const float* __restrict__ Wk,
                             float* __restrict__ k_ws) {
  __shared__ float As[64 * BKk];      // [row][w], stride 60
  __shared__ float Bs[BKk * 64];      // [w][col]
  const int tid = threadIdx.x;
  const int v0 = blockIdx.x * 64, n0 = blockIdx.y * 64;
  const int ty = tid >> 4, tx = tid & 15;
  f32x2 acc2[4][2] = {};   // [row][colpair]: cols (0,1) and (2,3)
  for (int s = 0; s < 5; ++s) {
    const int w0 = s * BKk;
    __syncthreads();
    for (int f = tid; f < 64 * 15; f += 256) {
      int row = f / 15, c4 = f % 15;
      int v = v0 + row;
      float4 g4 = (v < VOCAB) ? *(const float4*)&glove[(size_t)v * WDn + w0 + c4 * 4]
                              : make_float4(0.f, 0.f, 0.f, 0.f);
      *(float4*)&As[row * BKk + c4 * 4] = g4;
    }
    for (int f = tid; f < BKk * 16; f += 256) {
      int row = f / 16, c4 = f % 16;
      *(float4*)&Bs[row * 64 + c4 * 4] = *(const float4*)&Wk[(size_t)(w0 + row) * EMBD + n0 + c4 * 4];
    }
    __syncthreads();
    for (int w = 0; w < BKk; ++w) {
      f32x4 bv = *(const f32x4*)&Bs[w * 64 + tx * 4];
      f32x2 bl = lo2(bv), bh = hi2(bv);
      f32x2 a01, a23;
      a01.x = As[(ty * 4 + 0) * BKk + w];
      a01.y = As[(ty * 4 + 1) * BKk + w];
      a23.x = As[(ty * 4 + 2) * BKk + w];
      a23.y = As[(ty * 4 + 3) * BKk + w];
      pk_fma_blo(acc2[0][0], a01, bl); pk_fma_blo(acc2[0][1], a01, bh);
      pk_fma_bhi(acc2[1][0], a01, bl); pk_fma_bhi(acc2[1][1], a01, bh);
      pk_fma_blo(acc2[2][0], a23, bl); pk_fma_blo(acc2[2][1], a23, bh);
      pk_fma_bhi(acc2[3][0], a23, bl); pk_fma_bhi(acc2[3][1], a23, bh);
    }
  }
#pragma unroll
  for (int i = 0; i < 4; ++i) {
    int v = v0 + ty * 4 + i;
    if (v < VOCAB) {
      float4 st = make_float4(acc2[i][0].x, acc2[i][0].y, acc2[i][1].x, acc2[i][1].y);
      *(float4*)&k_ws[(size_t)v * EMBD + n0 + tx * 4] = st;
    }
  }
}

// ---------------- K3: scores + gumbel noise + per-chunk argmax ----------------
template<bool FULL>
__device__ __forceinline__ void score_epi(const f32x2 (&acc)[4][8],
                                          int v0, int tx, int ty, int rowtile, int h,
                                          int chunk, float* __restrict__ pval,
                                          int* __restrict__ pidx) {
#pragma unroll
  for (int i = 0; i < 4; ++i) {
    const int r = rowtile * 64 + ty * 4 + i;     // 0..511 within head
    const int b = r >> 7, q = r & 127;
    const uint32_t base = (uint32_t)((b * NH + h) * NQn + q) * (uint32_t)VOCAB;
    float best = -INFINITY; int bidx = 0x7fffffff;
#pragma unroll
    for (int j = 0; j < 8; ++j) {
      int v = v0 + tx + 16 * j;
      if (FULL || v < VOCAB) {
        float g = gumbel_ll(base + (uint32_t)v);
        float val = (acc[i][j].x + acc[i][j].y) - g;   // q pre-scaled by 0.125 (exact)
        if (val > best || (val == best && v < bidx)) { best = val; bidx = v; }
      }
    }
#pragma unroll
    for (int m = 8; m >= 1; m >>= 1) {
      float ov = __shfl_xor(best, m, 64);
      int   oi = __shfl_xor(bidx, m, 64);
      if (ov > best || (ov == best && oi < bidx)) { best = ov; bidx = oi; }
    }
    if (tx == 0) {
      int prow = h * 512 + r;
      pval[(size_t)prow * NCHUNK + chunk] = best;
      pidx[(size_t)prow * NCHUNK + chunk] = bidx;
    }
  }
}

__global__ __launch_bounds__(256, 2) void score_kernel(
                             const float* __restrict__ q_ws,
                             const float* __restrict__ k_ws,
                             float* __restrict__ pval,
                             int* __restrict__ pidx) {
  __shared__ float Qs[64 * 68];
  __shared__ float Ks[128 * 68];
  const int tid = threadIdx.x;
  const int chunk = blockIdx.x, rowtile = blockIdx.y, h = blockIdx.z;
  const int v0 = chunk * VCHUNK;
  const int ty = tid >> 4, tx = tid & 15;

  for (int f = tid; f < 64 * 16; f += 256) {
    int row = f >> 4, c4 = f & 15;
    f32x4 qv = *(const f32x4*)&q_ws[(size_t)(rowtile * 64 + row) * EMBD + h * DHn + c4 * 4];
    qv *= 0.125f;                                    // fold scale (2^-3, exact)
    *(f32x4*)&Qs[row * 68 + c4 * 4] = qv;
  }
  for (int f = tid; f < 128 * 16; f += 256) {
    int row = f >> 4, c4 = f & 15;
    int v = v0 + row;
    f32x4 k4 = {0.f, 0.f, 0.f, 0.f};
    if (v < VOCAB) k4 = *(const f32x4*)&k_ws[(size_t)v * EMBD + h * DHn + c4 * 4];
    *(f32x4*)&Ks[row * 68 + c4 * 4] = k4;
  }
  __syncthreads();

  f32x2 acc[4][8] = {};
#pragma unroll 1
  for (int d0 = 0; d0 < DHn; d0 += 4) {
    const float* kb = &Ks[tx * 68 + d0];
    f32x4 k0 = *(const f32x4*)(kb + 0 * 16 * 68);
    f32x4 k1 = *(const f32x4*)(kb + 1 * 16 * 68);
    f32x4 k2 = *(const f32x4*)(kb + 2 * 16 * 68);
    f32x4 k3 = *(const f32x4*)(kb + 3 * 16 * 68);
    f32x4 k4 = *(const f32x4*)(kb + 4 * 16 * 68);
    f32x4 k5 = *(const f32x4*)(kb + 5 * 16 * 68);
    f32x4 k6 = *(const f32x4*)(kb + 6 * 16 * 68);
    f32x4 k7 = *(const f32x4*)(kb + 7 * 16 * 68);
#pragma unroll
    for (int i = 0; i < 4; ++i) {
      f32x4 qv = *(const f32x4*)&Qs[(ty * 4 + i) * 68 + d0];
      f32x2 ql = lo2(qv), qh = hi2(qv);
      pk_fma(acc[i][0], ql, lo2(k0)); pk_fma(acc[i][0], qh, hi2(k0));
      pk_fma(acc[i][1], ql, lo2(k1)); pk_fma(acc[i][1], qh, hi2(k1));
      pk_fma(acc[i][2], ql, lo2(k2)); pk_fma(acc[i][2], qh, hi2(k2));
      pk_fma(acc[i][3], ql, lo2(k3)); pk_fma(acc[i][3], qh, hi2(k3));
      pk_fma(acc[i][4], ql, lo2(k4)); pk_fma(acc[i][4], qh, hi2(k4));
      pk_fma(acc[i][5], ql, lo2(k5)); pk_fma(acc[i][5], qh, hi2(k5));
      pk_fma(acc[i][6], ql, lo2(k6)); pk_fma(acc[i][6], qh, hi2(k6));
      pk_fma(acc[i][7], ql, lo2(k7)); pk_fma(acc[i][7], qh, hi2(k7));
    }
  }

  if (v0 + VCHUNK <= VOCAB)
    score_epi<true>(acc, v0, tx, ty, rowtile, h, chunk, pval, pidx);
  else
    score_epi<false>(acc, v0, tx, ty, rowtile, h, chunk, pval, pidx);
}

// ---------------- K4: reduce chunk partials -> final argmax ----------------
__global__ __launch_bounds__(256, 4) void argmax_reduce_kernel(
                                     const float* __restrict__ pval,
                                     const int* __restrict__ pidx,
                                     int* __restrict__ idxf) {
  const int tid = threadIdx.x;
  const int wave = tid >> 6, lane = tid & 63;
  const int row = blockIdx.x * 4 + wave;   // 0..4095 = h*512 + (b*128+q)
  float best = -INFINITY; int bidx = 0x7fffffff;
  for (int c = lane; c < NCHUNK; c += 64) {
    float v = pval[(size_t)row * NCHUNK + c];
    int   i = pidx[(size_t)row * NCHUNK + c];
    if (v > best || (v == best && i < bidx)) { best = v; bidx = i; }
  }
#pragma unroll
  for (int m = 32; m >= 1; m >>= 1) {
    float ov = __shfl_xor(best, m, 64);
    int   oi = __shfl_xor(bidx, m, 64);
    if (ov > best || (ov == best && oi < bidx)) { best = ov; bidx = oi; }
  }
  if (lane == 0) {
    int h = row >> 9, r = row & 511, b = r >> 7, q = r & 127;
    idxf[(b * NH + h) * NQn + q] = bidx;
  }
}

// ---------------- K5: gather + V projection + out proj + residual ----------------
__global__ __launch_bounds__(256, 4) void out_kernel(
                           const float* __restrict__ queries,
                           const float* __restrict__ glove,
                           const float* __restrict__ Wv,
                           const float* __restrict__ Wout,
                           const float* __restrict__ b_out,
                           const int* __restrict__ idxf,
                           float* __restrict__ out) {
  __shared__ float gl[4][NH][WDn];   // 38400 B
  __shared__ float vrow[4][EMBD];    // 8192 B
  __shared__ int idxs[4][NH];
  const int tid = threadIdx.x;
  const int r0 = blockIdx.x * 4;
  if (tid < 32) {
    int rr = tid >> 3, hh = tid & 7;
    int r = r0 + rr, b = r >> 7, q = r & 127;
    idxs[rr][hh] = idxf[(b * NH + hh) * NQn + q];
  }
  __syncthreads();
  for (int f = tid; f < 32 * 75; f += 256) {
    int rp = f / 75, c4 = f % 75;
    int rr = rp >> 3, hh = rp & 7;
    *(float4*)&gl[rr][hh][c4 * 4] = *(const float4*)&glove[(size_t)idxs[rr][hh] * WDn + c4 * 4];
  }
  __syncthreads();
  for (int e = tid; e < EMBD; e += 256) {
    float a0 = 0.f, a1 = 0.f, a2 = 0.f, a3 = 0.f;
    int hh = e >> 6;
    for (int w = 0; w < WDn; ++w) {
      float wv = Wv[(size_t)w * EMBD + e];
      a0 += gl[0][hh][w] * wv; a1 += gl[1][hh][w] * wv;
      a2 += gl[2][hh][w] * wv; a3 += gl[3][hh][w] * wv;
    }
    vrow[0][e] = a0; vrow[1][e] = a1; vrow[2][e] = a2; vrow[3][e] = a3;
  }
  __syncthreads();
  for (int j = tid; j < EMBD; j += 256) {
    float a0 = 0.f, a1 = 0.f, a2 = 0.f, a3 = 0.f;
    for (int e = 0; e < EMBD; ++e) {
      float wo = Wout[(size_t)e * QD + j];
      a0 += vrow[0][e] * wo; a1 += vrow[1][e] * wo;
      a2 += vrow[2][e] * wo; a3 += vrow[3][e] * wo;
    }
    float bb = b_out[j];
    out[(size_t)(r0 + 0) * QD + j] = queries[(size_t)(r0 + 0) * QD + j] + a0 + bb;
    out[(size_t)(r0 + 1) * QD + j] = queries[(size_t)(r0 + 1) * QD + j] + a1 + bb;
    out[(size_t)(r0 + 2) * QD + j] = queries[(size_t)(r0 + 2) * QD + j] + a2 + bb;
    out[(size_t)(r0 + 3) * QD + j] = queries[(size_t)(r0 + 3) * QD + j] + a3 + bb;
  }
}

extern "C" void kernel_launch(void* const* d_in, const int* in_sizes, int n_in,
                              void* d_out, int out_size, void* d_ws, size_t ws_size,
                              hipStream_t stream) {
  const float* queries = (const float*)d_in[0];
  const float* glove   = (const float*)d_in[1];
  const float* Wq      = (const float*)d_in[2];
  const float* Wk      = (const float*)d_in[3];
  const float* Wv      = (const float*)d_in[4];
  const float* Wout    = (const float*)d_in[5];
  const float* b_out   = (const float*)d_in[6];
  const float* ln_g    = (const float*)d_in[7];
  const float* ln_b    = (const float*)d_in[8];
  float* out = (float*)d_out;

  // workspace layout (floats): q[512*512] | k[20000*512] | pval[4096*157] | pidx | idxf
  float* ws   = (float*)d_ws;
  float* q_ws = ws;
  float* k_ws = q_ws + (size_t)NB * NQn * EMBD;
  float* pval = k_ws + (size_t)VOCAB * EMBD;
  int*   pidx = (int*)(pval + (size_t)NH * 512 * NCHUNK);
  int*   idxf = (int*)((float*)pidx + (size_t)NH * 512 * NCHUNK);

  hipLaunchKernelGGL(ln_qproj_kernel, dim3(128, 2), dim3(256), 0, stream,
                     queries, Wq, ln_g, ln_b, q_ws);
  hipLaunchKernelGGL(kproj_kernel, dim3(313, 8), dim3(256), 0, stream,
                     glove, Wk, k_ws);
  hipLaunchKernelGGL(score_kernel, dim3(NCHUNK, 8, NH), dim3(256), 0, stream,
                     q_ws, k_ws, pval, pidx);
  hipLaunchKernelGGL(argmax_reduce_kernel, dim3(1024), dim3(256), 0, stream,
                     pval, pidx, idxf);
  hipLaunchKernelGGL(out_kernel, dim3(128), dim3(256), 0, stream,
                     queries, glove, Wv, Wout, b_out, idxf, out);
}